// Round 5
// baseline (57.724 us; speedup 1.0000x reference)
//
#include <hip/hip_runtime.h>
#include <hip/hip_bf16.h>
#include <hip/hip_fp16.h>

typedef __bf16 bf16x8 __attribute__((ext_vector_type(8)));
typedef float  f32x4  __attribute__((ext_vector_type(4)));
typedef _Float16 h2   __attribute__((ext_vector_type(2)));

#define MAIN_BLOCKS 2048

#if defined(__has_builtin)
#  if __has_builtin(__builtin_amdgcn_fdot2)
#    define HAVE_FDOT2 1
#  else
#    define HAVE_FDOT2 0
#  endif
#else
#  define HAVE_FDOT2 0
#endif

// Each wave processes tiles of 16 states with mfma_f32_16x16x32_bf16.
// A-frag: lane holds A[m=lane&15][k=8*(lane>>4)+e (+32 for kstep1)]  (h1, computed in-place)
// B-frag: lane holds B[k=8*(lane>>4)+e+32*ks][n=(lane&15)+16*t]     (W2, preloaded)
// D:      lane holds C[m=4*(lane>>4)+r][n=(lane&15)+16*t]           (verified layout)
// Only the total sum of logits is needed -> no cross-lane epilogue.
//
// R4 post-mortem: __launch_bounds__(256,1) is only a FLOOR on waves/EU; the
// allocator still targeted max occupancy (VGPR=64) and rematerialized the
// ~124-VGPR weight set every tile (~317 VALU instr/tile vs ~115 ideal).
// amdgpu_waves_per_eu(1,2) caps the occupancy TARGET at 2 waves/EU ->
// 256-VGPR budget -> weights stay resident. asm keep-alives pin the preloads.
__global__ __launch_bounds__(256)
__attribute__((amdgpu_waves_per_eu(1, 2)))
void qloss_main(
    const float* __restrict__ states, const float* __restrict__ W1,
    const float* __restrict__ b1, const float* __restrict__ W2,
    const float* __restrict__ b2, const float* __restrict__ W3,
    int n_states, double* __restrict__ partials)
{
    const int lane = threadIdx.x & 63;
    const int wave = threadIdx.x >> 6;
    const int g = lane >> 4;     // k-group 0..3
    const int r = lane & 15;     // row within A-tile / col within D-tile

    // ---- per-lane constant preload ----
    float b1r[16];
#if HAVE_FDOT2
    h2 w1p[2][16];               // W1 packed as f16 pairs: (i0,i1),(i2,i3)
#else
    float w1r[4][16];
#endif
#pragma unroll
    for (int j = 0; j < 16; ++j) {
        const int k = 8*g + (j & 7) + 32*(j >> 3);
        b1r[j] = b1[k];
#if HAVE_FDOT2
        w1p[0][j] = h2{(_Float16)W1[0*64 + k], (_Float16)W1[1*64 + k]};
        w1p[1][j] = h2{(_Float16)W1[2*64 + k], (_Float16)W1[3*64 + k]};
#else
#pragma unroll
        for (int i = 0; i < 4; ++i) w1r[i][j] = W1[i*64 + k];
#endif
    }

    bf16x8 w2f[4][2];
#pragma unroll
    for (int t = 0; t < 4; ++t)
#pragma unroll
        for (int ks = 0; ks < 2; ++ks)
#pragma unroll
            for (int e = 0; e < 8; ++e) {
                const int k = 8*g + e + 32*ks;
                w2f[t][ks][e] = (__bf16)W2[k*64 + (r + 16*t)];
            }

    float b2r[4], w3r[4];
#pragma unroll
    for (int t = 0; t < 4; ++t) { b2r[t] = b2[r + 16*t]; w3r[t] = W3[r + 16*t]; }

    // Pin all loop-invariant preloads in registers: block the compiler from
    // sinking the loads into the hot loop (rematerialization).
#pragma unroll
    for (int j = 0; j < 16; ++j) {
        asm volatile("" : "+v"(b1r[j]));
#if HAVE_FDOT2
        asm volatile("" : "+v"(w1p[0][j]), "+v"(w1p[1][j]));
#else
        asm volatile("" : "+v"(w1r[0][j]), "+v"(w1r[1][j]),
                          "+v"(w1r[2][j]), "+v"(w1r[3][j]));
#endif
    }
#pragma unroll
    for (int t = 0; t < 4; ++t) {
        asm volatile("" : "+v"(w2f[t][0]), "+v"(w2f[t][1]));
        asm volatile("" : "+v"(b2r[t]), "+v"(w3r[t]));
    }

    const int ntiles = n_states >> 4;
    const int waves_per_blk = blockDim.x >> 6;
    const int nwaves = gridDim.x * waves_per_blk;
    const float4* __restrict__ st4 = (const float4*)states;

    float psum = 0.f;
    const int tile0 = blockIdx.x * waves_per_blk + wave;
    float4 xc = {0.f, 0.f, 0.f, 0.f};
    if (tile0 < ntiles) xc = st4[tile0*16 + r];   // lanes 16..63 replicate lanes 0..15

    for (int tile = tile0; tile < ntiles; tile += nwaves) {
        // software prefetch of next tile (clamped; keeps 1 load in flight)
        const int nxt = tile + nwaves;
        const int nidx = (nxt < ntiles) ? nxt : tile;
        const float4 xn = st4[nidx*16 + r];

        // layer 1: h1 = relu(x@W1 + b1), produced directly in A-fragment layout
#if HAVE_FDOT2
        const h2 x01 = {(_Float16)xc.x, (_Float16)xc.y};
        const h2 x23 = {(_Float16)xc.z, (_Float16)xc.w};
#endif
        bf16x8 af[2];
#pragma unroll
        for (int ks = 0; ks < 2; ++ks)
#pragma unroll
            for (int e = 0; e < 8; ++e) {
                const int j = ks*8 + e;
#if HAVE_FDOT2
                float t = __builtin_amdgcn_fdot2(x01, w1p[0][j], b1r[j], false);
                t       = __builtin_amdgcn_fdot2(x23, w1p[1][j], t, false);
#else
                float t = fmaf(xc.x, w1r[0][j], b1r[j]);
                t = fmaf(xc.y, w1r[1][j], t);
                t = fmaf(xc.z, w1r[2][j], t);
                t = fmaf(xc.w, w1r[3][j], t);
#endif
                af[ks][e] = (__bf16)fmaxf(t, 0.f);
            }

        // layer 2 (MFMA, b2 folded into acc init) + epilogue (relu * W3)
#pragma unroll
        for (int t4 = 0; t4 < 4; ++t4) {
            f32x4 acc = { b2r[t4], b2r[t4], b2r[t4], b2r[t4] };
            acc = __builtin_amdgcn_mfma_f32_16x16x32_bf16(af[0], w2f[t4][0], acc, 0, 0, 0);
            acc = __builtin_amdgcn_mfma_f32_16x16x32_bf16(af[1], w2f[t4][1], acc, 0, 0, 0);
#pragma unroll
            for (int rr = 0; rr < 4; ++rr)
                psum = fmaf(fmaxf(acc[rr], 0.f), w3r[t4], psum);
        }

        xc = xn;
    }

    // ---- block reduction -> one double partial per block ----
#pragma unroll
    for (int off = 32; off; off >>= 1) psum += __shfl_xor(psum, off, 64);
    __shared__ float wpart[4];
    if (lane == 0) wpart[wave] = psum;
    __syncthreads();
    if (threadIdx.x == 0)
        partials[blockIdx.x] = (double)(wpart[0] + wpart[1] + wpart[2] + wpart[3]);
}

// 1 block, 256 threads: wave w computes net(e_w) in fp32; thread 0 combines.
__global__ __launch_bounds__(256) void qloss_finalize(
    const float* __restrict__ W1, const float* __restrict__ b1,
    const float* __restrict__ W2, const float* __restrict__ b2,
    const float* __restrict__ W3, const float* __restrict__ b3,
    const double* __restrict__ partials, int nparts,
    int n_states, float* __restrict__ out)
{
    const int lane = threadIdx.x & 63;
    const int wave = threadIdx.x >> 6;

    __shared__ float  dlog[4];
    __shared__ double wsum[4];

    // denominator logits: one-hot state index == wave
    float h1 = fmaxf(W1[wave*64 + lane] + b1[lane], 0.f);
    float acc = b2[lane];
    for (int k = 0; k < 64; ++k)
        acc = fmaf(__shfl(h1, k, 64), W2[k*64 + lane], acc);
    float c = fmaxf(acc, 0.f) * W3[lane];
#pragma unroll
    for (int off = 32; off; off >>= 1) c += __shfl_xor(c, off, 64);
    if (lane == 0) dlog[wave] = c + b3[0];

    // sum block partials
    double ps = 0.0;
    for (int i = threadIdx.x; i < nparts; i += blockDim.x) ps += partials[i];
#pragma unroll
    for (int off = 32; off; off >>= 1) ps += __shfl_xor(ps, off, 64);
    if (lane == 0) wsum[wave] = ps;

    __syncthreads();
    if (threadIdx.x == 0) {
        const double S = wsum[0] + wsum[1] + wsum[2] + wsum[3];
        double m = dlog[0];
        for (int i = 1; i < 4; ++i) m = fmax(m, (double)dlog[i]);
        double e = 0.0;
        for (int i = 0; i < 4; ++i) e += exp((double)dlog[i] - m);
        const double lse = m + log(e);
        const double nn = (double)n_states;
        const double logits_sum = S + nn * (double)b3[0];
        out[0] = (float)(-(logits_sum - nn * lse));
    }
}

extern "C" void kernel_launch(void* const* d_in, const int* in_sizes, int n_in,
                              void* d_out, int out_size, void* d_ws, size_t ws_size,
                              hipStream_t stream)
{
    const float* states = (const float*)d_in[0];
    const float* W1 = (const float*)d_in[1];
    const float* b1 = (const float*)d_in[2];
    const float* W2 = (const float*)d_in[3];
    const float* b2 = (const float*)d_in[4];
    const float* W3 = (const float*)d_in[5];
    const float* b3 = (const float*)d_in[6];
    float* out = (float*)d_out;

    const int n_states = in_sizes[0] / 4;

    int nb = MAIN_BLOCKS;
    const size_t max_parts = ws_size / sizeof(double);
    if ((size_t)nb > max_parts) nb = (int)max_parts;
    if (nb < 1) nb = 1;
    double* partials = (double*)d_ws;

    qloss_main<<<nb, 256, 0, stream>>>(states, W1, b1, W2, b2, W3, n_states, partials);
    qloss_finalize<<<1, 256, 0, stream>>>(W1, b1, W2, b2, W3, b3, partials, nb, n_states, out);
}

// Round 6
// 52.929 us; speedup vs baseline: 1.0906x; 1.0906x over previous
//
#include <hip/hip_runtime.h>
#include <hip/hip_bf16.h>
#include <hip/hip_fp16.h>
#include <stdint.h>

typedef __bf16 bf16x8 __attribute__((ext_vector_type(8)));
typedef float  f32x4  __attribute__((ext_vector_type(4)));
typedef _Float16 h2   __attribute__((ext_vector_type(2)));
typedef int    i32x4  __attribute__((ext_vector_type(4)));

#define MAIN_BLOCKS 1024

// Each wave processes tiles of 16 states with mfma_f32_16x16x32_bf16.
// A-frag: lane holds A[m=lane&15][k=8*(lane>>4)+e (+32 for ks=1)]  (h1, computed in-place)
// B-frag: lane holds B[k=8*(lane>>4)+e+32*ks][n=(lane&15)+16*t]   (W2, preloaded)
// D:      lane holds C[m=4*(lane>>4)+rr][n=(lane&15)+16*t]        (verified layout)
// Only the total sum of logits is needed -> no cross-lane epilogue.
//
// R5 post-mortem: with pins, VGPR=92 (weights resident) yet VALU-busy still
// ~34us == R1/R4. The junk is structural: bf16 sub-register element inserts
// (v_perm/v_bfi per af element) + cvt overhead at the MFMA interface.
// Fix: build A-fragments as i32 words via explicit v_cvt_pk_bf16_f32 asm
// (32-bit element writes are free), bit_cast to bf16x8.
__global__ __launch_bounds__(256) void qloss_main(
    const float* __restrict__ states, const float* __restrict__ W1,
    const float* __restrict__ b1, const float* __restrict__ W2,
    const float* __restrict__ b2, const float* __restrict__ W3,
    int n_states, double* __restrict__ partials)
{
    const int lane = threadIdx.x & 63;
    const int wave = threadIdx.x >> 6;
    const int g = lane >> 4;     // k-group 0..3
    const int r = lane & 15;     // row within A-tile / col within D-tile

    // ---- per-lane constant preload ----
    float b1r[16];
    h2 w1p[2][16];               // W1 packed as f16 pairs: (i0,i1),(i2,i3)
#pragma unroll
    for (int j = 0; j < 16; ++j) {
        const int k = 8*g + (j & 7) + 32*(j >> 3);
        b1r[j] = b1[k];
        w1p[0][j] = h2{(_Float16)W1[0*64 + k], (_Float16)W1[1*64 + k]};
        w1p[1][j] = h2{(_Float16)W1[2*64 + k], (_Float16)W1[3*64 + k]};
    }

    bf16x8 w2f[4][2];
#pragma unroll
    for (int t = 0; t < 4; ++t)
#pragma unroll
        for (int ks = 0; ks < 2; ++ks)
#pragma unroll
            for (int e = 0; e < 8; ++e) {
                const int k = 8*g + e + 32*ks;
                w2f[t][ks][e] = (__bf16)W2[k*64 + (r + 16*t)];
            }

    float b2r[4], w3r[4];
#pragma unroll
    for (int t = 0; t < 4; ++t) { b2r[t] = b2[r + 16*t]; w3r[t] = W3[r + 16*t]; }

    // Pin loop-invariant preloads in registers (R5: proven to give residency).
#pragma unroll
    for (int j = 0; j < 16; ++j) {
        asm("" : "+v"(b1r[j]));
        asm("" : "+v"(w1p[0][j]), "+v"(w1p[1][j]));
    }
#pragma unroll
    for (int t = 0; t < 4; ++t) {
        asm("" : "+v"(w2f[t][0]), "+v"(w2f[t][1]));
        asm("" : "+v"(b2r[t]), "+v"(w3r[t]));
    }

    const int ntiles = n_states >> 4;
    const int waves_per_blk = blockDim.x >> 6;
    const int nwaves = gridDim.x * waves_per_blk;
    const float4* __restrict__ st4 = (const float4*)states;

    float ps0 = 0.f, ps1 = 0.f;
    const int tile0 = blockIdx.x * waves_per_blk + wave;
    float4 xc = {0.f, 0.f, 0.f, 0.f};
    if (tile0 < ntiles) xc = st4[tile0*16 + r];   // lanes 16..63 replicate lanes 0..15

    for (int tile = tile0; tile < ntiles; tile += nwaves) {
        // software prefetch of next tile (clamped; keeps 1 load in flight)
        const int nxt = tile + nwaves;
        const int nidx = (nxt < ntiles) ? nxt : tile;
        const float4 xn = st4[nidx*16 + r];

        // layer 1: h1 = relu(x@W1 + b1) -> A-fragment, built as i32 words
        const h2 x01 = {(_Float16)xc.x, (_Float16)xc.y};
        const h2 x23 = {(_Float16)xc.z, (_Float16)xc.w};
        i32x4 aw0, aw1;
#pragma unroll
        for (int ks = 0; ks < 2; ++ks) {
#pragma unroll
            for (int w = 0; w < 4; ++w) {
                const int j0 = ks*8 + 2*w, j1 = j0 + 1;
                float t0 = __builtin_amdgcn_fdot2(x01, w1p[0][j0], b1r[j0], false);
                t0       = __builtin_amdgcn_fdot2(x23, w1p[1][j0], t0, false);
                float t1 = __builtin_amdgcn_fdot2(x01, w1p[0][j1], b1r[j1], false);
                t1       = __builtin_amdgcn_fdot2(x23, w1p[1][j1], t1, false);
                t0 = fmaxf(t0, 0.f);
                t1 = fmaxf(t1, 0.f);
                int w32;
                asm("v_cvt_pk_bf16_f32 %0, %1, %2" : "=v"(w32) : "v"(t0), "v"(t1));
                if (ks == 0) aw0[w] = w32; else aw1[w] = w32;
            }
        }
        const bf16x8 af0 = __builtin_bit_cast(bf16x8, aw0);
        const bf16x8 af1 = __builtin_bit_cast(bf16x8, aw1);

        // layer 2 (MFMA, b2 folded into acc init) + epilogue (relu * W3)
#pragma unroll
        for (int t4 = 0; t4 < 4; ++t4) {
            f32x4 acc = { b2r[t4], b2r[t4], b2r[t4], b2r[t4] };
            acc = __builtin_amdgcn_mfma_f32_16x16x32_bf16(af0, w2f[t4][0], acc, 0, 0, 0);
            acc = __builtin_amdgcn_mfma_f32_16x16x32_bf16(af1, w2f[t4][1], acc, 0, 0, 0);
            ps0 = fmaf(fmaxf(acc[0], 0.f), w3r[t4], ps0);
            ps1 = fmaf(fmaxf(acc[1], 0.f), w3r[t4], ps1);
            ps0 = fmaf(fmaxf(acc[2], 0.f), w3r[t4], ps0);
            ps1 = fmaf(fmaxf(acc[3], 0.f), w3r[t4], ps1);
        }

        xc = xn;
    }

    // ---- block reduction -> one double partial per block ----
    float psum = ps0 + ps1;
#pragma unroll
    for (int off = 32; off; off >>= 1) psum += __shfl_xor(psum, off, 64);
    __shared__ float wpart[4];
    if (lane == 0) wpart[wave] = psum;
    __syncthreads();
    if (threadIdx.x == 0)
        partials[blockIdx.x] = (double)(wpart[0] + wpart[1] + wpart[2] + wpart[3]);
}

// 1 block, 256 threads: wave w computes net(e_w) in fp32; thread 0 combines.
__global__ __launch_bounds__(256) void qloss_finalize(
    const float* __restrict__ W1, const float* __restrict__ b1,
    const float* __restrict__ W2, const float* __restrict__ b2,
    const float* __restrict__ W3, const float* __restrict__ b3,
    const double* __restrict__ partials, int nparts,
    int n_states, float* __restrict__ out)
{
    const int lane = threadIdx.x & 63;
    const int wave = threadIdx.x >> 6;

    __shared__ float  dlog[4];
    __shared__ double wsum[4];

    // denominator logits: one-hot state index == wave
    float h1 = fmaxf(W1[wave*64 + lane] + b1[lane], 0.f);
    float acc = b2[lane];
    for (int k = 0; k < 64; ++k)
        acc = fmaf(__shfl(h1, k, 64), W2[k*64 + lane], acc);
    float c = fmaxf(acc, 0.f) * W3[lane];
#pragma unroll
    for (int off = 32; off; off >>= 1) c += __shfl_xor(c, off, 64);
    if (lane == 0) dlog[wave] = c + b3[0];

    // sum block partials
    double ps = 0.0;
    for (int i = threadIdx.x; i < nparts; i += blockDim.x) ps += partials[i];
#pragma unroll
    for (int off = 32; off; off >>= 1) ps += __shfl_xor(ps, off, 64);
    if (lane == 0) wsum[wave] = ps;

    __syncthreads();
    if (threadIdx.x == 0) {
        const double S = wsum[0] + wsum[1] + wsum[2] + wsum[3];
        double m = dlog[0];
        for (int i = 1; i < 4; ++i) m = fmax(m, (double)dlog[i]);
        double e = 0.0;
        for (int i = 0; i < 4; ++i) e += exp((double)dlog[i] - m);
        const double lse = m + log(e);
        const double nn = (double)n_states;
        const double logits_sum = S + nn * (double)b3[0];
        out[0] = (float)(-(logits_sum - nn * lse));
    }
}

extern "C" void kernel_launch(void* const* d_in, const int* in_sizes, int n_in,
                              void* d_out, int out_size, void* d_ws, size_t ws_size,
                              hipStream_t stream)
{
    const float* states = (const float*)d_in[0];
    const float* W1 = (const float*)d_in[1];
    const float* b1 = (const float*)d_in[2];
    const float* W2 = (const float*)d_in[3];
    const float* b2 = (const float*)d_in[4];
    const float* W3 = (const float*)d_in[5];
    const float* b3 = (const float*)d_in[6];
    float* out = (float*)d_out;

    const int n_states = in_sizes[0] / 4;

    int nb = MAIN_BLOCKS;
    const size_t max_parts = ws_size / sizeof(double);
    if ((size_t)nb > max_parts) nb = (int)max_parts;
    if (nb < 1) nb = 1;
    double* partials = (double*)d_ws;

    qloss_main<<<nb, 256, 0, stream>>>(states, W1, b1, W2, b2, W3, n_states, partials);
    qloss_finalize<<<1, 256, 0, stream>>>(W1, b1, W2, b2, W3, b3, partials, nb, n_states, out);
}